// Round 13
// 479.605 us; speedup vs baseline: 1.3271x; 1.0318x over previous
//
#include <hip/hip_runtime.h>
#include <math.h>

#define EPSV 1e-5f
#define GF_RELU 1
#define GF_ACCUM 2

typedef unsigned long long u64;
typedef unsigned int u32;
typedef unsigned short u16;
typedef float v2f __attribute__((ext_vector_type(2)));
typedef short bf16x8 __attribute__((ext_vector_type(8)));
typedef float f32x4 __attribute__((ext_vector_type(4)));

static const int Bn = 8;
static const int Nmax = 2048;
static const int KNN_K = 8;

// ---- split-bf16 helpers: fp32 -> (hi,lo) bf16 pair ---------------------------
__device__ __forceinline__ u32 split_pack(float v) {
  u32 u = __float_as_uint(v);
  float r = v - __uint_as_float(u & 0xffff0000u);
  return (u >> 16) | (__float_as_uint(r) & 0xffff0000u);
}

__device__ __forceinline__ void split4(float4 v, uint2& hp, uint2& lp) {
  u32 u0 = __float_as_uint(v.x), u1 = __float_as_uint(v.y);
  u32 u2 = __float_as_uint(v.z), u3 = __float_as_uint(v.w);
  float r0 = v.x - __uint_as_float(u0 & 0xffff0000u);
  float r1 = v.y - __uint_as_float(u1 & 0xffff0000u);
  float r2 = v.z - __uint_as_float(u2 & 0xffff0000u);
  float r3 = v.w - __uint_as_float(u3 & 0xffff0000u);
  hp.x = (u0 >> 16) | (u1 & 0xffff0000u);
  hp.y = (u2 >> 16) | (u3 & 0xffff0000u);
  lp.x = (__float_as_uint(r0) >> 16) | (__float_as_uint(r1) & 0xffff0000u);
  lp.y = (__float_as_uint(r2) >> 16) | (__float_as_uint(r3) & 0xffff0000u);
}

__device__ __forceinline__ void depair4(uint4 p, uint2& hp, uint2& lp) {
  hp.x = (p.x & 0xffffu) | (p.y << 16);
  hp.y = (p.z & 0xffffu) | (p.w << 16);
  lp.x = (p.x >> 16) | (p.y & 0xffff0000u);
  lp.y = (p.z >> 16) | (p.w & 0xffff0000u);
}

// ---------------- precompute: fold BN into scale/bias, zero picks ----------------
__global__ void precompute_kernel(const float* __restrict__ bn_g, const float* __restrict__ bn_b,
                                  const float* __restrict__ bp1,
                                  float* __restrict__ sc, float* __restrict__ bb,
                                  float* __restrict__ picks) {
  int t = threadIdx.x;
  if (t < 128) {
    float s = bn_g[t] / sqrtf(1.0f + EPSV);
    sc[t] = s;
    bb[t] = bp1[t] * s + bn_b[t];
  }
  for (int i = t; i < Bn * 256; i += blockDim.x) picks[i] = 0.0f;
}

// ---------------- repack Ws/Wn [L][h][d][e] -> [L][d][h*128+e] (fp32 fallback) --
__global__ void repack_ws_kernel(const float* __restrict__ Ws, const float* __restrict__ Wn,
                                 float* __restrict__ WsP, float* __restrict__ WnP) {
  int idx = blockIdx.x * 256 + threadIdx.x;
  const int total = 3 * 4 * 128 * 128;
  if (idx >= total) return;
  int e = idx & 127, d = (idx >> 7) & 127, h = (idx >> 14) & 3, L = idx >> 16;
  size_t dst = ((size_t)L * 128 + d) * 512 + h * 128 + e;
  WsP[dst] = Ws[idx];
  WnP[dst] = Wn[idx];
}

// ---------------- repack+split for MFMA path -----------------------------------
__global__ void repack_split_kernel(const float* __restrict__ Ws, const float* __restrict__ Wn,
                                    const float* __restrict__ Wg, const float* __restrict__ Wp1,
                                    const float* __restrict__ Wp2, const float* __restrict__ W1,
                                    const float* __restrict__ W2,
                                    u32* __restrict__ Wc,
                                    u16* __restrict__ WgTh, u16* __restrict__ WgTl,
                                    u32* __restrict__ Wp1T, u32* __restrict__ Wp2T,
                                    u16* __restrict__ W1Th, u16* __restrict__ W1Tl,
                                    u16* __restrict__ W2Th, u16* __restrict__ W2Tl) {
  int idx = blockIdx.x * 256 + threadIdx.x;
  if (idx < 393216) {
    int k = idx & 255, col = (idx >> 8) & 511, L = idx >> 17;
    float v;
    if (k < 128)
      v = Ws[(((size_t)(L * 4 + (col >> 7))) * 128 + k) * 128 + (col & 127)];
    else
      v = Wn[(((size_t)(L * 4 + (col >> 7))) * 128 + (k - 128)) * 128 + (col & 127)];
    Wc[idx] = split_pack(v);
  } else if (idx < 589824) {
    int i2 = idx - 393216;
    int k = i2 & 511, col = (i2 >> 9) & 127, L = i2 >> 16;
    u32 pr = split_pack(Wg[((size_t)L * 512 + k) * 128 + col]);
    size_t a = (size_t)L * 65536 + (size_t)(col >> 4) * 8192 +
               (size_t)(k >> 3) * 128 + (col & 15) * 8 + (k & 7);
    WgTh[a] = (u16)pr;
    WgTl[a] = (u16)(pr >> 16);
  } else if (idx < 655360) {
    int i3 = idx - 589824;
    int k = i3 & 511, col = i3 >> 9;
    Wp1T[i3] = split_pack(Wp1[(size_t)k * 128 + col]);
  } else if (idx < 671744) {
    int i4 = idx - 655360;
    int k = i4 & 127, col = i4 >> 7;
    Wp2T[i4] = split_pack(Wp2[(size_t)k * 128 + col]);
  } else if (idx < 720896) {
    int i5 = idx - 671744;
    int k = i5 & 127, col = (i5 >> 7) & 127, L = i5 >> 14;
    u32 pr = split_pack(W1[((size_t)L * 128 + k) * 128 + col]);
    size_t a = (size_t)L * 16384 + (size_t)(col >> 4) * 2048 +
               (size_t)(k >> 3) * 128 + (col & 15) * 8 + (k & 7);
    W1Th[a] = (u16)pr;
    W1Tl[a] = (u16)(pr >> 16);
  } else if (idx < 770048) {
    int i6 = idx - 720896;
    int k = i6 & 127, col = (i6 >> 7) & 127, L = i6 >> 14;
    u32 pr = split_pack(W2[((size_t)L * 128 + k) * 128 + col]);
    size_t a = (size_t)L * 16384 + (size_t)(col >> 4) * 2048 +
               (size_t)(k >> 3) * 128 + (col & 15) * 8 + (k & 7);
    W2Th[a] = (u16)pr;
    W2Tl[a] = (u16)(pr >> 16);
  }
}

// ---------------- KNN: group-cached minima + DIRECT adj atomicOr ---------------
// lane 0 sets both adjacency bits per selection, eliminating the knn_idx
// round-trip and the build_adj kernel. ADJ must be zeroed before launch.
template<int T>
__global__ __launch_bounds__(256) void knn_sel_kernel(const float* __restrict__ cent,
                                                      u32* __restrict__ adj, int Ni) {
  int i = blockIdx.x * 4 + (threadIdx.x >> 6);
  int b = blockIdx.y, lane = threadIdx.x & 63;
  const float2* cb = (const float2*)(cent + (size_t)b * Ni * 2);
  float2 ci = cb[i];
  u32 d2b[T];
#pragma unroll
  for (int t = 0; t < T; ++t) {
    int j = (t << 6) + lane;
    float2 cj = cb[j];
    float dx = __fsub_rn(ci.x, cj.x);
    float dy = __fsub_rn(ci.y, cj.y);
    float d2 = __fadd_rn(__fmul_rn(dx, dx), __fmul_rn(dy, dy));
    d2b[t] = __float_as_uint(d2);   // d2 >= 0 -> u32-monotone
  }
  constexpr int G = T / 4;
  u32 gmin[G];
  int gidx[G];
#pragma unroll
  for (int g = 0; g < G; ++g) {
    u32 m = d2b[g * 4]; int mi = g * 4;
#pragma unroll
    for (int e = 1; e < 4; ++e) {
      if (d2b[g * 4 + e] < m) { m = d2b[g * 4 + e]; mi = g * 4 + e; }
    }
    gmin[g] = m; gidx[g] = mi;
  }
  for (int r = 0; r < KNN_K; ++r) {
    u32 bd; int bt;
    if (G >= 2) {
      u32 a = gmin[0]; int ai = gidx[0];
      u32 bv = gmin[G / 2]; int bi = gidx[G / 2];
#pragma unroll
      for (int g = 1; g < G / 2; ++g) {
        if (gmin[g] < a) { a = gmin[g]; ai = gidx[g]; }
        if (gmin[G / 2 + g] < bv) { bv = gmin[G / 2 + g]; bi = gidx[G / 2 + g]; }
      }
      bd = a; bt = ai;
      if (bv < bd) { bd = bv; bt = bi; }
    } else {
      bd = gmin[0]; bt = gidx[0];
    }
    u64 key = ((u64)bd << 32) | (u32)((bt << 6) | lane);
    for (int off = 32; off >= 1; off >>= 1) {
      u64 o = __shfl_xor(key, off, 64);
      if (o < key) key = o;
    }
    u32 jsel = (u32)key;
    if (lane == 0) {
      atomicOr(&adj[((size_t)(b * Nmax + i)) * 64 + (jsel >> 5)], 1u << (jsel & 31));
      atomicOr(&adj[((size_t)(b * Nmax + (int)jsel)) * 64 + (i >> 5)], 1u << (i & 31));
    }
    int tsel = __builtin_amdgcn_readfirstlane((int)(jsel >> 6));
    bool owner = (int)(jsel & 63) == lane;
    int gsel = tsel >> 2;
#pragma unroll
    for (int g = 0; g < G; ++g) {
      if (g == gsel) {            // wave-uniform scalar branch, g compile-time
        if (owner) {
#pragma unroll
          for (int e = 0; e < 4; ++e)
            if (g * 4 + e == tsel) d2b[g * 4 + e] = 0xFFFFFFFFu;
          u32 m = d2b[g * 4]; int mi = g * 4;
#pragma unroll
          for (int e = 1; e < 4; ++e)
            if (d2b[g * 4 + e] < m) { m = d2b[g * 4 + e]; mi = g * 4 + e; }
          gmin[g] = m; gidx[g] = mi;
        }
      }
    }
  }
}

// ---------------- layernorm: one wave per row (fallback paths) -----------------
__global__ __launch_bounds__(256) void layernorm_kernel(const float* __restrict__ x,
                                                        const float* __restrict__ g,
                                                        const float* __restrict__ be,
                                                        float* __restrict__ xn) {
  int row = blockIdx.x * 4 + (threadIdx.x >> 6);
  int lane = threadIdx.x & 63;
  const float* xr = x + (size_t)row * 128;
  float v1 = xr[lane], v2 = xr[lane + 64];
  float s = v1 + v2;
  for (int off = 32; off >= 1; off >>= 1) s += __shfl_xor(s, off, 64);
  float mean = s / 128.0f;
  float d1 = v1 - mean, d2 = v2 - mean;
  float q = d1 * d1 + d2 * d2;
  for (int off = 32; off >= 1; off >>= 1) q += __shfl_xor(q, off, 64);
  float rs = rsqrtf(q / 128.0f + EPSV);
  float* xo = xn + (size_t)row * 128;
  xo[lane] = d1 * rs * g[lane] + be[lane];
  xo[lane + 64] = d2 * rs * g[lane + 64] + be[lane + 64];
}

// ---------------- neighbor-mean aggregation + degree (2 nodes/block, ILP2) -----
// fused3: writes m as split-pair u32 in FRAGMENT-TILED layout (mpair != null):
//   addr = (grow>>4)*2048 + (t>>3)*128 + (grow&15)*8 + (t&7), grow = b*Ni+i
// else: fp32 row-major m (fallback paths).
__global__ __launch_bounds__(256) void aggregate_kernel(const u32* __restrict__ adj,
                                                        const float* __restrict__ xn,
                                                        float* __restrict__ m,
                                                        u32* __restrict__ mpair,
                                                        float* __restrict__ dinv, int Ni) {
  int sub = threadIdx.x >> 7;
  int t = threadIdx.x & 127;
  int i = blockIdx.x * 2 + sub, b = blockIdx.y;
  __shared__ int cnt[2];
  extern __shared__ int list[];
  int* lst = list + sub * Ni;
  if (t == 0) cnt[sub] = 0;
  __syncthreads();
  int wpr = Ni >> 5;
  for (int w = t; w < wpr; w += 128) {
    u32 bits = adj[((size_t)(b * Nmax + i)) * 64 + w];
    while (bits) {
      int bit = __ffs(bits) - 1;
      bits &= bits - 1;
      int pos = atomicAdd(&cnt[sub], 1);
      lst[pos] = (w << 5) + bit;
    }
  }
  __syncthreads();
  int d = cnt[sub];
  float a0 = 0.0f, a1 = 0.0f;
  int k = 0;
  for (; k + 2 <= d; k += 2) {
    a0 += xn[((size_t)b * Ni + lst[k]) * 128 + t];
    a1 += xn[((size_t)b * Ni + lst[k + 1]) * 128 + t];
  }
  if (k < d) a0 += xn[((size_t)b * Ni + lst[k]) * 128 + t];
  float mv = (a0 + a1) / (float)d;
  if (mpair) {
    int grow = b * Ni + i;
    mpair[(size_t)(grow >> 4) * 2048 + (size_t)(t >> 3) * 128 + (grow & 15) * 8 + (t & 7)] =
        split_pack(mv);
  } else {
    m[((size_t)b * Ni + i) * 128 + t] = mv;
  }
  if (t == 0) dinv[b * Nmax + i] = 1.0f / sqrtf((float)d);
}

// ---------------- MFMA split-bf16 GEMM 1: H = relu([xn|m] @ [Ws;Wn] + bs) ------
// A k<128 (xn) staged via LDS split4 (4 steps); A k>=128 (m) direct-loaded as
// fragment-tiled split pairs (prefetched 1 step ahead, depair in registers).
// Output H hi/lo planes fragment-tiled: (row>>4)*8192 + (col>>3)*128 + (row&15)*8 + (col&7)
__global__ __launch_bounds__(256) void attn_gemm1_kernel(
    const float* __restrict__ XN, const u32* __restrict__ MP,
    const u32* __restrict__ Wc, const float* __restrict__ bs,
    u16* __restrict__ Hh, u16* __restrict__ Hl, int M) {
  __shared__ u16 Ah[128][40], Al[128][40], Bh[128][40], Bl[128][40];
  int tid = threadIdx.x;
  int lane = tid & 63, w = tid >> 6;
  int wr = w >> 1, wc = w & 1;
  int lr = lane & 15, lk = (lane >> 4) * 8;
  int rowBase = blockIdx.y * 128, colBase = blockIdx.x * 128;
  f32x4 acc[4][4] = {};
  int arow = tid >> 1, aq = (tid & 1) * 16;
  int bcol = tid >> 1, bq = (tid & 1) * 16;

  float4 af[4];
  uint4 bf[4];
  uint4 mp[8];
  {
    const float* Ap = XN + (size_t)(rowBase + arow) * 128 + aq;
#pragma unroll
    for (int q = 0; q < 4; ++q) af[q] = *(const float4*)(Ap + 4 * q);
    const u32* Bp = Wc + (size_t)(colBase + bcol) * 256 + bq;
#pragma unroll
    for (int q = 0; q < 4; ++q) bf[q] = *(const uint4*)(Bp + 4 * q);
  }
  for (int t = 0; t < 8; ++t) {
    __syncthreads();
    if (t < 4) {
#pragma unroll
      for (int q = 0; q < 4; ++q) {
        uint2 hp, lp;
        split4(af[q], hp, lp);
        *(uint2*)&Ah[arow][aq + 4 * q] = hp;
        *(uint2*)&Al[arow][aq + 4 * q] = lp;
      }
    }
#pragma unroll
    for (int q = 0; q < 4; ++q) {
      uint2 hp, lp;
      depair4(bf[q], hp, lp);
      *(uint2*)&Bh[bcol][bq + 4 * q] = hp;
      *(uint2*)&Bl[bcol][bq + 4 * q] = lp;
    }
    __syncthreads();
    // ---- build A fragments for this step (consume mp BEFORE prefetch) ----
    bf16x8 ah[4], al[4], bh[4], bl[4];
    if (t < 4) {
#pragma unroll
      for (int mi = 0; mi < 4; ++mi) {
        int ar = wr * 64 + mi * 16 + lr;
        ah[mi] = *(const bf16x8*)&Ah[ar][lk];
        al[mi] = *(const bf16x8*)&Al[ar][lk];
      }
    } else {
#pragma unroll
      for (int mi = 0; mi < 4; ++mi) {
        uint2 h0, l0, h1, l1;
        depair4(mp[mi * 2], h0, l0);
        depair4(mp[mi * 2 + 1], h1, l1);
        uint4 hx, lx;
        hx.x = h0.x; hx.y = h0.y; hx.z = h1.x; hx.w = h1.y;
        lx.x = l0.x; lx.y = l0.y; lx.z = l1.x; lx.w = l1.y;
        ah[mi] = *(const bf16x8*)&hx;
        al[mi] = *(const bf16x8*)&lx;
      }
    }
    // ---- prefetch for t+1 ----
    if (t + 1 < 4) {
      const float* Ap = XN + (size_t)(rowBase + arow) * 128 + (t + 1) * 32 + aq;
#pragma unroll
      for (int q = 0; q < 4; ++q) af[q] = *(const float4*)(Ap + 4 * q);
    } else if (t + 1 < 8) {
      int ks = (t + 1 - 4) * 4 + (lane >> 4);
#pragma unroll
      for (int mi = 0; mi < 4; ++mi) {
        const u32* p = MP + (size_t)((rowBase >> 4) + wr * 4 + mi) * 2048 +
                       (size_t)ks * 128 + lr * 8;
        mp[mi * 2] = *(const uint4*)p;
        mp[mi * 2 + 1] = *(const uint4*)(p + 4);
      }
    }
    if (t + 1 < 8) {
      const u32* Bp = Wc + (size_t)(colBase + bcol) * 256 + (t + 1) * 32 + bq;
#pragma unroll
      for (int q = 0; q < 4; ++q) bf[q] = *(const uint4*)(Bp + 4 * q);
    }
#pragma unroll
    for (int ni = 0; ni < 4; ++ni) {
      int bc = wc * 64 + ni * 16 + lr;
      bh[ni] = *(const bf16x8*)&Bh[bc][lk];
      bl[ni] = *(const bf16x8*)&Bl[bc][lk];
    }
#pragma unroll
    for (int mi = 0; mi < 4; ++mi)
#pragma unroll
      for (int ni = 0; ni < 4; ++ni) {
        f32x4 c = acc[mi][ni];
        c = __builtin_amdgcn_mfma_f32_16x16x32_bf16(al[mi], bh[ni], c, 0, 0, 0);
        c = __builtin_amdgcn_mfma_f32_16x16x32_bf16(ah[mi], bl[ni], c, 0, 0, 0);
        c = __builtin_amdgcn_mfma_f32_16x16x32_bf16(ah[mi], bh[ni], c, 0, 0, 0);
        acc[mi][ni] = c;
      }
  }
  int rq = (lane >> 4) * 4;
#pragma unroll
  for (int ni = 0; ni < 4; ++ni) {
    int col = colBase + wc * 64 + ni * 16 + lr;
    float bv = bs[col];
    size_t cbase = (size_t)(col >> 3) * 128 + (col & 7);
#pragma unroll
    for (int mi = 0; mi < 4; ++mi) {
      int rb = (rowBase >> 4) + wr * 4 + mi;
#pragma unroll
      for (int r = 0; r < 4; ++r) {
        float v = fmaxf(acc[mi][ni][r] + bv, 0.0f);
        u32 pr = split_pack(v);
        size_t o = (size_t)rb * 8192 + cbase + (size_t)(rq + r) * 8;
        Hh[o] = (u16)pr;
        Hl[o] = (u16)(pr >> 16);
      }
    }
  }
}

// ---------------- fused GEMM2+LN2+FFN+qp, 16-row tiles, fragment-tiled ---------
__global__ __launch_bounds__(256) void attn2_ffn16_kernel(
    const u16* __restrict__ Hh, const u16* __restrict__ Hl,
    const u16* __restrict__ Bgh, const u16* __restrict__ Bgl,
    const float* __restrict__ bg, const float* __restrict__ g,
    const float* __restrict__ be,
    const u16* __restrict__ W1h, const u16* __restrict__ W1l,
    const float* __restrict__ b1,
    const u16* __restrict__ W2h, const u16* __restrict__ W2l,
    const float* __restrict__ b2, float* __restrict__ x,
    const float* __restrict__ Wq, const float* __restrict__ dinv,
    float* __restrict__ PV, int niShift, int M) {
  __shared__ float XF[16][132];
  __shared__ u16 XH[16][136], XL[16][136];
  __shared__ float QS[16];
  int tid = threadIdx.x;
  int lane = tid & 63, w = tid >> 6;
  int lr = lane & 15, lk = (lane >> 4) * 8, rq = (lane >> 4) * 4;
  int rowBase = blockIdx.x * 16;
  int colW = w * 32;
  int fo = (lane >> 4) * 128 + lr * 8;   // per-lane offset within a kt block

  // ---- phase 1: acc = H @ Wg (K=512), fragment-tiled direct loads ----
  f32x4 acc[2] = {};
  {
    const u16* pAh = Hh + (size_t)blockIdx.x * 8192;
    const u16* pAl = Hl + (size_t)blockIdx.x * 8192;
    const u16* pBh = Bgh + (size_t)(w * 2) * 8192;
    const u16* pBl = Bgl + (size_t)(w * 2) * 8192;
    bf16x8 ah = *(const bf16x8*)(pAh + fo);
    bf16x8 al = *(const bf16x8*)(pAl + fo);
    bf16x8 b0h = *(const bf16x8*)(pBh + fo);
    bf16x8 b0l = *(const bf16x8*)(pBl + fo);
    bf16x8 b1h = *(const bf16x8*)(pBh + 8192 + fo);
    bf16x8 b1l = *(const bf16x8*)(pBl + 8192 + fo);
    for (int kt = 0; kt < 16; ++kt) {
      bf16x8 cah = ah, cal = al, cb0h = b0h, cb0l = b0l, cb1h = b1h, cb1l = b1l;
      if (kt + 1 < 16) {
        int off = (kt + 1) * 512 + fo;
        ah = *(const bf16x8*)(pAh + off);
        al = *(const bf16x8*)(pAl + off);
        b0h = *(const bf16x8*)(pBh + off);
        b0l = *(const bf16x8*)(pBl + off);
        b1h = *(const bf16x8*)(pBh + 8192 + off);
        b1l = *(const bf16x8*)(pBl + 8192 + off);
      }
      acc[0] = __builtin_amdgcn_mfma_f32_16x16x32_bf16(cal, cb0h, acc[0], 0, 0, 0);
      acc[0] = __builtin_amdgcn_mfma_f32_16x16x32_bf16(cah, cb0l, acc[0], 0, 0, 0);
      acc[0] = __builtin_amdgcn_mfma_f32_16x16x32_bf16(cah, cb0h, acc[0], 0, 0, 0);
      acc[1] = __builtin_amdgcn_mfma_f32_16x16x32_bf16(cal, cb1h, acc[1], 0, 0, 0);
      acc[1] = __builtin_amdgcn_mfma_f32_16x16x32_bf16(cah, cb1l, acc[1], 0, 0, 0);
      acc[1] = __builtin_amdgcn_mfma_f32_16x16x32_bf16(cah, cb1h, acc[1], 0, 0, 0);
    }
  }
  // ---- phase 2: x += acc + bg; stash into XF ----
#pragma unroll
  for (int ni = 0; ni < 2; ++ni) {
    int col = colW + ni * 16 + lr;
    float bv = bg[col];
#pragma unroll
    for (int r = 0; r < 4; ++r) {
      int rowL = rq + r;
      size_t o = (size_t)(rowBase + rowL) * 128 + col;
      float v = x[o] + acc[ni][r] + bv;
      x[o] = v;
      XF[rowL][col] = v;
    }
  }
  __syncthreads();
  // ---- phase 3: LN rows (4 rows/wave); write hi/lo planes into XH/XL ----
#pragma unroll
  for (int rr = 0; rr < 4; ++rr) {
    int rowL = w * 4 + rr;
    float v1 = XF[rowL][lane], v2 = XF[rowL][64 + lane];
    float s = v1 + v2;
    for (int off = 32; off >= 1; off >>= 1) s += __shfl_xor(s, off, 64);
    float mean = s / 128.0f;
    float d1 = v1 - mean, d2 = v2 - mean;
    float q = d1 * d1 + d2 * d2;
    for (int off = 32; off >= 1; off >>= 1) q += __shfl_xor(q, off, 64);
    float rs = rsqrtf(q / 128.0f + EPSV);
    float xn1 = d1 * rs * g[lane] + be[lane];
    float xn2 = d2 * rs * g[lane + 64] + be[lane + 64];
    u32 p1 = split_pack(xn1);
    u32 p2 = split_pack(xn2);
    XH[rowL][lane] = (u16)p1;  XL[rowL][lane] = (u16)(p1 >> 16);
    XH[rowL][64 + lane] = (u16)p2;  XL[rowL][64 + lane] = (u16)(p2 >> 16);
  }
  __syncthreads();
  // ---- phase 4: acc1 = xn @ W1 (K=128); A from LDS planes, B fragment-tiled ----
  f32x4 acc1[2] = {};
  {
    const u16* pBh = W1h + (size_t)(w * 2) * 2048;
    const u16* pBl = W1l + (size_t)(w * 2) * 2048;
#pragma unroll
    for (int kt = 0; kt < 4; ++kt) {
      int k0 = kt * 32 + lk;
      int off = kt * 512 + fo;
      bf16x8 ah = *(const bf16x8*)&XH[lr][k0];
      bf16x8 al = *(const bf16x8*)&XL[lr][k0];
      bf16x8 b0h = *(const bf16x8*)(pBh + off);
      bf16x8 b0l = *(const bf16x8*)(pBl + off);
      bf16x8 b1h = *(const bf16x8*)(pBh + 2048 + off);
      bf16x8 b1l = *(const bf16x8*)(pBl + 2048 + off);
      acc1[0] = __builtin_amdgcn_mfma_f32_16x16x32_bf16(al, b0h, acc1[0], 0, 0, 0);
      acc1[0] = __builtin_amdgcn_mfma_f32_16x16x32_bf16(ah, b0l, acc1[0], 0, 0, 0);
      acc1[0] = __builtin_amdgcn_mfma_f32_16x16x32_bf16(ah, b0h, acc1[0], 0, 0, 0);
      acc1[1] = __builtin_amdgcn_mfma_f32_16x16x32_bf16(al, b1h, acc1[1], 0, 0, 0);
      acc1[1] = __builtin_amdgcn_mfma_f32_16x16x32_bf16(ah, b1l, acc1[1], 0, 0, 0);
      acc1[1] = __builtin_amdgcn_mfma_f32_16x16x32_bf16(ah, b1h, acc1[1], 0, 0, 0);
    }
  }
  __syncthreads();
  // ---- phase 5: hidden = relu(acc1 + b1) -> XH/XL planes; zero QS ----
  if (tid < 16) QS[tid] = 0.0f;
#pragma unroll
  for (int ni = 0; ni < 2; ++ni) {
    int col = colW + ni * 16 + lr;
    float bv = b1[col];
#pragma unroll
    for (int r = 0; r < 4; ++r) {
      int rowL = rq + r;
      float v = fmaxf(acc1[ni][r] + bv, 0.0f);
      u32 pr = split_pack(v);
      XH[rowL][col] = (u16)pr;
      XL[rowL][col] = (u16)(pr >> 16);
    }
  }
  __syncthreads();
  // ---- phase 6: acc2 = hidden @ W2 (K=128) ----
  f32x4 acc2[2] = {};
  {
    const u16* pBh = W2h + (size_t)(w * 2) * 2048;
    const u16* pBl = W2l + (size_t)(w * 2) * 2048;
#pragma unroll
    for (int kt = 0; kt < 4; ++kt) {
      int k0 = kt * 32 + lk;
      int off = kt * 512 + fo;
      bf16x8 ah = *(const bf16x8*)&XH[lr][k0];
      bf16x8 al = *(const bf16x8*)&XL[lr][k0];
      bf16x8 b0h = *(const bf16x8*)(pBh + off);
      bf16x8 b0l = *(const bf16x8*)(pBl + off);
      bf16x8 b1h = *(const bf16x8*)(pBh + 2048 + off);
      bf16x8 b1l = *(const bf16x8*)(pBl + 2048 + off);
      acc2[0] = __builtin_amdgcn_mfma_f32_16x16x32_bf16(al, b0h, acc2[0], 0, 0, 0);
      acc2[0] = __builtin_amdgcn_mfma_f32_16x16x32_bf16(ah, b0l, acc2[0], 0, 0, 0);
      acc2[0] = __builtin_amdgcn_mfma_f32_16x16x32_bf16(ah, b0h, acc2[0], 0, 0, 0);
      acc2[1] = __builtin_amdgcn_mfma_f32_16x16x32_bf16(al, b1h, acc2[1], 0, 0, 0);
      acc2[1] = __builtin_amdgcn_mfma_f32_16x16x32_bf16(ah, b1l, acc2[1], 0, 0, 0);
      acc2[1] = __builtin_amdgcn_mfma_f32_16x16x32_bf16(ah, b1h, acc2[1], 0, 0, 0);
    }
  }
  // ---- phase 7: x += acc2 + b2 ; fused qp accumulation ----
  float qp[4] = {0.0f, 0.0f, 0.0f, 0.0f};
#pragma unroll
  for (int ni = 0; ni < 2; ++ni) {
    int col = colW + ni * 16 + lr;
    float bv = b2[col];
    float wq = Wq[col];
#pragma unroll
    for (int r = 0; r < 4; ++r) {
      int rowL = rq + r;
      size_t o = (size_t)(rowBase + rowL) * 128 + col;
      float v = x[o] + acc2[ni][r] + bv;
      x[o] = v;
      qp[r] += v * wq;
    }
  }
#pragma unroll
  for (int r = 0; r < 4; ++r) {
    qp[r] += __shfl_xor(qp[r], 1, 64);
    qp[r] += __shfl_xor(qp[r], 2, 64);
    qp[r] += __shfl_xor(qp[r], 4, 64);
    qp[r] += __shfl_xor(qp[r], 8, 64);
  }
  if (lr == 0) {
#pragma unroll
    for (int r = 0; r < 4; ++r) atomicAdd(&QS[rq + r], qp[r]);
  }
  __syncthreads();
  if (tid < 16) {
    int node = rowBase + tid;
    int bb = node >> niShift;
    int ii = node & ((1 << niShift) - 1);
    PV[bb * Nmax + ii] = dinv[bb * Nmax + ii] * QS[tid];
  }
}

// ---------------- MFMA preconv1: H = split(relu((feats@Wp1)*sc + bb)) ----------
__global__ __launch_bounds__(256) void preconv1_kernel(
    const float* __restrict__ F, const u32* __restrict__ WT,
    const float* __restrict__ sc, const float* __restrict__ bb,
    u32* __restrict__ H, int M) {
  __shared__ u16 Ah[64][40], Al[64][40], Bh[128][40], Bl[128][40];
  int tid = threadIdx.x;
  int lane = tid & 63, w = tid >> 6;
  int wr = w >> 1, wc = w & 1;
  int lr = lane & 15, lk = (lane >> 4) * 8;
  int rowBase = blockIdx.x * 64;
  f32x4 acc[2][4] = {};
  int arow = tid >> 2, aq = (tid & 3) * 8;
  int bcol = tid >> 1, bq = (tid & 1) * 16;

  float4 af[2];
  uint4 bf[4];
  {
    const float* Ap = F + (size_t)(rowBase + arow) * 512 + aq;
    af[0] = *(const float4*)Ap;
    af[1] = *(const float4*)(Ap + 4);
    const u32* Bp = WT + (size_t)bcol * 512 + bq;
#pragma unroll
    for (int q = 0; q < 4; ++q) bf[q] = *(const uint4*)(Bp + 4 * q);
  }
  for (int t = 0; t < 16; ++t) {
    __syncthreads();
    {
      uint2 hp, lp;
      split4(af[0], hp, lp);
      *(uint2*)&Ah[arow][aq] = hp; *(uint2*)&Al[arow][aq] = lp;
      split4(af[1], hp, lp);
      *(uint2*)&Ah[arow][aq + 4] = hp; *(uint2*)&Al[arow][aq + 4] = lp;
#pragma unroll
      for (int q = 0; q < 4; ++q) {
        depair4(bf[q], hp, lp);
        *(uint2*)&Bh[bcol][bq + 4 * q] = hp;
        *(uint2*)&Bl[bcol][bq + 4 * q] = lp;
      }
    }
    __syncthreads();
    if (t + 1 < 16) {
      int k0 = (t + 1) * 32;
      const float* Ap = F + (size_t)(rowBase + arow) * 512 + k0 + aq;
      af[0] = *(const float4*)Ap;
      af[1] = *(const float4*)(Ap + 4);
      const u32* Bp = WT + (size_t)bcol * 512 + k0 + bq;
#pragma unroll
      for (int q = 0; q < 4; ++q) bf[q] = *(const uint4*)(Bp + 4 * q);
    }
    bf16x8 ah[2], al[2], bh[4], bl[4];
#pragma unroll
    for (int mi = 0; mi < 2; ++mi) {
      int ar = wr * 32 + mi * 16 + lr;
      ah[mi] = *(const bf16x8*)&Ah[ar][lk];
      al[mi] = *(const bf16x8*)&Al[ar][lk];
    }
#pragma unroll
    for (int ni = 0; ni < 4; ++ni) {
      int bc = wc * 64 + ni * 16 + lr;
      bh[ni] = *(const bf16x8*)&Bh[bc][lk];
      bl[ni] = *(const bf16x8*)&Bl[bc][lk];
    }
#pragma unroll
    for (int mi = 0; mi < 2; ++mi)
#pragma unroll
      for (int ni = 0; ni < 4; ++ni) {
        f32x4 c = acc[mi][ni];
        c = __builtin_amdgcn_mfma_f32_16x16x32_bf16(al[mi], bh[ni], c, 0, 0, 0);
        c = __builtin_amdgcn_mfma_f32_16x16x32_bf16(ah[mi], bl[ni], c, 0, 0, 0);
        c = __builtin_amdgcn_mfma_f32_16x16x32_bf16(ah[mi], bh[ni], c, 0, 0, 0);
        acc[mi][ni] = c;
      }
  }
  int rq = (lane >> 4) * 4;
#pragma unroll
  for (int ni = 0; ni < 4; ++ni) {
    int col = wc * 64 + ni * 16 + lr;
    float s = sc[col], b = bb[col];
#pragma unroll
    for (int mi = 0; mi < 2; ++mi)
#pragma unroll
      for (int r = 0; r < 4; ++r) {
        int row = rowBase + wr * 32 + mi * 16 + rq + r;
        float v = fmaxf(acc[mi][ni][r] * s + b, 0.0f);
        H[(size_t)row * 128 + col] = split_pack(v);
      }
  }
}

// ---------------- MFMA preconv2 + fused LN1: X = H@Wp2 + bp2 ; xn = LN(X) ------
__global__ __launch_bounds__(256) void preconv2_ln_kernel(
    const u32* __restrict__ H, const u32* __restrict__ WT,
    const float* __restrict__ bias, const float* __restrict__ g,
    const float* __restrict__ be, float* __restrict__ X,
    float* __restrict__ xn, int M) {
  __shared__ __align__(16) char smem[33792];
  u16* Ah = (u16*)smem;
  u16* Al = Ah + 64 * 40;
  u16* Bh = Al + 64 * 40;
  u16* Bl = Bh + 128 * 40;
  float* T = (float*)smem;
  int tid = threadIdx.x;
  int lane = tid & 63, w = tid >> 6;
  int wr = w >> 1, wc = w & 1;
  int lr = lane & 15, lk = (lane >> 4) * 8;
  int rowBase = blockIdx.x * 64;
  f32x4 acc[2][4] = {};
  int arow = tid >> 2, aq = (tid & 3) * 8;
  int bcol = tid >> 1, bq = (tid & 1) * 16;

  for (int kt = 0; kt < 4; ++kt) {
    __syncthreads();
    {
      const u32* Ap = H + (size_t)(rowBase + arow) * 128 + kt * 32 + aq;
      uint4 a0 = *(const uint4*)Ap, a1 = *(const uint4*)(Ap + 4);
      uint2 hp, lp;
      depair4(a0, hp, lp);
      *(uint2*)&Ah[arow * 40 + aq] = hp; *(uint2*)&Al[arow * 40 + aq] = lp;
      depair4(a1, hp, lp);
      *(uint2*)&Ah[arow * 40 + aq + 4] = hp; *(uint2*)&Al[arow * 40 + aq + 4] = lp;
      const u32* Bp = WT + (size_t)bcol * 128 + kt * 32 + bq;
#pragma unroll
      for (int q = 0; q < 4; ++q) {
        depair4(*(const uint4*)(Bp + 4 * q), hp, lp);
        *(uint2*)&Bh[bcol * 40 + bq + 4 * q] = hp;
        *(uint2*)&Bl[bcol * 40 + bq + 4 * q] = lp;
      }
    }
    __syncthreads();
    bf16x8 ah[2], al[2], bh[4], bl[4];
#pragma unroll
    for (int mi = 0; mi < 2; ++mi) {
      int ar = wr * 32 + mi * 16 + lr;
      ah[mi] = *(const bf16x8*)&Ah[ar * 40 + lk];
      al[mi] = *(const bf16x8*)&Al[ar * 40 + lk];
    }
#pragma unroll
    for (int ni = 0; ni < 4; ++ni) {
      int bc = wc * 64 + ni * 16 + lr;
      bh[ni] = *(const bf16x8*)&Bh[bc * 40 + lk];
      bl[ni] = *(const bf16x8*)&Bl[bc * 40 + lk];
    }
#pragma unroll
    for (int mi = 0; mi < 2; ++mi)
#pragma unroll
      for (int ni = 0; ni < 4; ++ni) {
        f32x4 c = acc[mi][ni];
        c = __builtin_amdgcn_mfma_f32_16x16x32_bf16(al[mi], bh[ni], c, 0, 0, 0);
        c = __builtin_amdgcn_mfma_f32_16x16x32_bf16(ah[mi], bl[ni], c, 0, 0, 0);
        c = __builtin_amdgcn_mfma_f32_16x16x32_bf16(ah[mi], bh[ni], c, 0, 0, 0);
        acc[mi][ni] = c;
      }
  }
  int rq = (lane >> 4) * 4;
  __syncthreads();
#pragma unroll
  for (int ni = 0; ni < 4; ++ni) {
    int col = wc * 64 + ni * 16 + lr;
    float bv = bias[col];
#pragma unroll
    for (int mi = 0; mi < 2; ++mi)
#pragma unroll
      for (int r = 0; r < 4; ++r) {
        int rowL = wr * 32 + mi * 16 + rq + r;
        float v = acc[mi][ni][r] + bv;
        X[(size_t)(rowBase + rowL) * 128 + col] = v;
        T[rowL * 132 + col] = v;
      }
  }
  __syncthreads();
  for (int rr = 0; rr < 16; ++rr) {
    int rowL = w * 16 + rr;
    float v1 = T[rowL * 132 + lane], v2 = T[rowL * 132 + 64 + lane];
    float s = v1 + v2;
    for (int off = 32; off >= 1; off >>= 1) s += __shfl_xor(s, off, 64);
    float mean = s / 128.0f;
    float d1 = v1 - mean, d2 = v2 - mean;
    float q = d1 * d1 + d2 * d2;
    for (int off = 32; off >= 1; off >>= 1) q += __shfl_xor(q, off, 64);
    float rs = rsqrtf(q / 128.0f + EPSV);
    size_t oo = (size_t)(rowBase + rowL) * 128;
    xn[oo + lane] = d1 * rs * g[lane] + be[lane];
    xn[oo + 64 + lane] = d2 * rs * g[lane + 64] + be[lane + 64];
  }
}

// ---------------- fp32 GEMM, TMx128 tile (fallback) ----------------------------
template<int TM>
__global__ __launch_bounds__(256) void gemm_kernel(
    const float* __restrict__ A, const float* __restrict__ W,
    const float* __restrict__ A2, const float* __restrict__ W2,
    const float* __restrict__ scale, const float* __restrict__ bias,
    float* __restrict__ C, int M, int N, int K, int flags) {
  constexpr int RPT = TM / 8;
  __shared__ float As[16][TM + 4];
  __shared__ float Bs[16][132];
  int tid = threadIdx.x;
  int tx = tid & 31;
  int ty = tid >> 5;
  int colBase = blockIdx.x * 128, rowBase = blockIdx.y * TM;
  v2f acc[RPT][2] = {};
  int ktiles = K >> 4;
  int total = (A2 ? 2 : 1) * ktiles;

  int arow = tid >> 2, aq = (tid & 3) * 4;
  int bk = tid >> 5, bc = (tid & 31) * 4;

  float4 pa, pb0, pb1;
  {
    if (TM == 64 || tid < TM * 4)
      pa = *(const float4*)(A + (size_t)(rowBase + arow) * K + aq);
    pb0 = *(const float4*)(W + (size_t)bk * N + colBase + bc);
    pb1 = *(const float4*)(W + (size_t)(bk + 8) * N + colBase + bc);
  }
  for (int t = 0; t < total; ++t) {
    if (TM == 64 || tid < TM * 4) {
      As[aq + 0][arow] = pa.x;
      As[aq + 1][arow] = pa.y;
      As[aq + 2][arow] = pa.z;
      As[aq + 3][arow] = pa.w;
    }
    *(float4*)&Bs[bk][bc] = pb0;
    *(float4*)&Bs[bk + 8][bc] = pb1;
    __syncthreads();
    if (t + 1 < total) {
      int tn = t + 1;
      const float* Ap = (tn >= ktiles) ? A2 : A;
      const float* Wp = (tn >= ktiles) ? W2 : W;
      int k0 = ((tn >= ktiles) ? tn - ktiles : tn) << 4;
      if (TM == 64 || tid < TM * 4)
        pa = *(const float4*)(Ap + (size_t)(rowBase + arow) * K + k0 + aq);
      pb0 = *(const float4*)(Wp + (size_t)(k0 + bk) * N + colBase + bc);
      pb1 = *(const float4*)(Wp + (size_t)(k0 + bk + 8) * N + colBase + bc);
    }
#pragma unroll
    for (int kk = 0; kk < 16; ++kk) {
      float a[RPT];
      v2f bv[2];
      if (RPT == 8) {
        *(float4*)&a[0] = *(const float4*)&As[kk][ty * 8];
        *(float4*)&a[4] = *(const float4*)&As[kk][ty * 8 + 4];
      } else {
        *(float4*)&a[0] = *(const float4*)&As[kk][ty * 4];
      }
      *(float4*)&bv[0] = *(const float4*)&Bs[kk][tx * 4];
#pragma unroll
      for (int r = 0; r < RPT; ++r)
#pragma unroll
        for (int c = 0; c < 2; ++c) acc[r][c] += a[r] * bv[c];
    }
    __syncthreads();
  }
#pragma unroll
  for (int r = 0; r < RPT; ++r) {
    int row = rowBase + ty * RPT + r;
    int col = colBase + tx * 4;
    float av[4];
    *(v2f*)&av[0] = acc[r][0];
    *(v2f*)&av[2] = acc[r][1];
    float4 v;
    float* vp = (float*)&v;
#pragma unroll
    for (int c = 0; c < 4; ++c) {
      float t = av[c];
      if (scale) t *= scale[col + c];
      if (bias) t += bias[col + c];
      if (flags & GF_RELU) t = fmaxf(t, 0.0f);
      vp[c] = t;
    }
    size_t o = (size_t)row * N + col;
    if (flags & GF_ACCUM) {
      float4 old = *(float4*)&C[o];
      v.x += old.x; v.y += old.y; v.z += old.z; v.w += old.w;
    }
    *(float4*)&C[o] = v;
  }
}

// ---------------- dual-operand 128x128-tile GEMM (fused2 fallback) -------------
__global__ __launch_bounds__(256) void gemm128dual_kernel(
    const float* __restrict__ A0, const float* __restrict__ W0,
    const float* __restrict__ A1, const float* __restrict__ W1,
    float* __restrict__ C0p, float* __restrict__ C1p, int M, int N) {
  const float* A = blockIdx.z ? A1 : A0;
  const float* W = blockIdx.z ? W1 : W0;
  float* C = blockIdx.z ? C1p : C0p;
  __shared__ float As[2][16][132];
  __shared__ float Bs[2][16][132];
  int tid = threadIdx.x;
  int tx = tid & 15;
  int ty = tid >> 4;
  int colBase = blockIdx.x * 128, rowBase = blockIdx.y * 128;
  v2f acc[8][4] = {};

  int arow = tid >> 1, aq = (tid & 1) * 8;
  int bk = tid >> 4, bq4 = (tid & 15) * 4;

  float4 pa0, pa1, pb0, pb1;
  {
    const float* ap = A + (size_t)(rowBase + arow) * 128 + aq;
    pa0 = *(const float4*)ap;
    pa1 = *(const float4*)(ap + 4);
    const float* bp = W + (size_t)bk * N + colBase;
    pb0 = *(const float4*)(bp + bq4);
    pb1 = *(const float4*)(bp + 64 + bq4);
  }
  for (int t = 0; t < 8; ++t) {
    int buf = t & 1;
    As[buf][aq + 0][arow] = pa0.x; As[buf][aq + 1][arow] = pa0.y;
    As[buf][aq + 2][arow] = pa0.z; As[buf][aq + 3][arow] = pa0.w;
    As[buf][aq + 4][arow] = pa1.x; As[buf][aq + 5][arow] = pa1.y;
    As[buf][aq + 6][arow] = pa1.z; As[buf][aq + 7][arow] = pa1.w;
    *(float4*)&Bs[buf][bk][bq4] = pb0;
    *(float4*)&Bs[buf][bk][64 + bq4] = pb1;
    __syncthreads();
    if (t + 1 < 8) {
      int k0 = (t + 1) << 4;
      const float* ap = A + (size_t)(rowBase + arow) * 128 + k0 + aq;
      pa0 = *(const float4*)ap;
      pa1 = *(const float4*)(ap + 4);
      const float* bp = W + (size_t)(k0 + bk) * N + colBase;
      pb0 = *(const float4*)(bp + bq4);
      pb1 = *(const float4*)(bp + 64 + bq4);
    }
#pragma unroll
    for (int kk = 0; kk < 16; ++kk) {
      float a[8];
      v2f bv[4];
      *(float4*)&a[0] = *(const float4*)&As[buf][kk][ty * 8];
      *(float4*)&a[4] = *(const float4*)&As[buf][kk][ty * 8 + 4];
      *(float4*)&bv[0] = *(const float4*)&Bs[buf][kk][tx * 4];
      *(float4*)&bv[2] = *(const float4*)&Bs[buf][kk][64 + tx * 4];
#pragma unroll
      for (int r = 0; r < 8; ++r)
#pragma unroll
        for (int c = 0; c < 4; ++c) acc[r][c] += a[r] * bv[c];
    }
  }
#pragma unroll
  for (int r = 0; r < 8; ++r) {
    int row = rowBase + ty * 8 + r;
#pragma unroll
    for (int h = 0; h < 2; ++h) {
      int col = colBase + h * 64 + tx * 4;
      float4 v;
      *(v2f*)&v.x = acc[r][h * 2 + 0];
      *(v2f*)&v.z = acc[r][h * 2 + 1];
      *(float4*)&C[(size_t)row * N + col] = v;
    }
  }
}

// ---------------- K-sliced 128x128-tile GEMM (fused fallback) ------------------
__global__ __launch_bounds__(256) void gemm128ks_kernel(
    const float* __restrict__ A, const float* __restrict__ W,
    float* __restrict__ P, int M, int K) {
  __shared__ float As[2][16][132];
  __shared__ float Bs[2][16][132];
  int tid = threadIdx.x;
  int tx = tid & 15;
  int ty = tid >> 4;
  int rowBase = blockIdx.y * 128;
  int kbase = blockIdx.z * 128;
  v2f acc[8][4] = {};

  int arow = tid >> 1, aq = (tid & 1) * 8;
  int bk = tid >> 4, bq4 = (tid & 15) * 4;

  float4 pa0, pa1, pb0, pb1;
  {
    const float* ap = A + (size_t)(rowBase + arow) * K + kbase + aq;
    pa0 = *(const float4*)ap;
    pa1 = *(const float4*)(ap + 4);
    const float* bp = W + (size_t)(kbase + bk) * 128;
    pb0 = *(const float4*)(bp + bq4);
    pb1 = *(const float4*)(bp + 64 + bq4);
  }
  for (int t = 0; t < 8; ++t) {
    int buf = t & 1;
    As[buf][aq + 0][arow] = pa0.x; As[buf][aq + 1][arow] = pa0.y;
    As[buf][aq + 2][arow] = pa0.z; As[buf][aq + 3][arow] = pa0.w;
    As[buf][aq + 4][arow] = pa1.x; As[buf][aq + 5][arow] = pa1.y;
    As[buf][aq + 6][arow] = pa1.z; As[buf][aq + 7][arow] = pa1.w;
    *(float4*)&Bs[buf][bk][bq4] = pb0;
    *(float4*)&Bs[buf][bk][64 + bq4] = pb1;
    __syncthreads();
    if (t + 1 < 8) {
      int k0 = kbase + ((t + 1) << 4);
      const float* ap = A + (size_t)(rowBase + arow) * K + k0 + aq;
      pa0 = *(const float4*)ap;
      pa1 = *(const float4*)(ap + 4);
      const float* bp = W + (size_t)(k0 + bk) * 128;
      pb0 = *(const float4*)(bp + bq4);
      pb1 = *(const float4*)(bp + 64 + bq4);
    }
#pragma unroll
    for (int kk = 0; kk < 16; ++kk) {
      float a[8];
      v2f bv[4];
      *(float4*)&a[0] = *(const float4*)&As[buf][kk][ty * 8];
      *(float4*)&a[4] = *(const float4*)&As[buf][kk][ty * 8 + 4];
      *(float4*)&bv[0] = *(const float4*)&Bs[buf][kk][tx * 4];
      *(float4*)&bv[2] = *(const float4*)&Bs[buf][kk][64 + tx * 4];
#pragma unroll
      for (int r = 0; r < 8; ++r)
#pragma unroll
        for (int c = 0; c < 4; ++c) acc[r][c] += a[r] * bv[c];
    }
  }
  float* dst = P + (size_t)blockIdx.z * M * 128;
#pragma unroll
  for (int r = 0; r < 8; ++r) {
    int row = rowBase + ty * 8 + r;
#pragma unroll
    for (int h = 0; h < 2; ++h) {
      int col = h * 64 + tx * 4;
      float4 v;
      *(v2f*)&v.x = acc[r][h * 2 + 0];
      *(v2f*)&v.z = acc[r][h * 2 + 1];
      *(float4*)&dst[(size_t)row * 128 + col] = v;
    }
  }
}

// ---------------- preconv2 psum4 (fallback, no LN) -----------------------------
__global__ __launch_bounds__(256) void gemm_psum4_kernel(
    const float* __restrict__ P, const float* __restrict__ sc,
    const float* __restrict__ bb, const float* __restrict__ W,
    const float* __restrict__ bias, float* __restrict__ C, int M) {
  __shared__ float As[16][36];
  __shared__ float Bs[16][132];
  int tid = threadIdx.x;
  int tx = tid & 31;
  int ty = tid >> 5;
  int rowBase = blockIdx.y * 32;
  v2f acc[4][2] = {};
  const size_t PS = (size_t)M * 128;

  int arow = tid >> 2, aq = (tid & 3) * 4;
  int bk = tid >> 5, bc = (tid & 31) * 4;

  float4 p0, p1, p2, p3, s4, b4, pb0, pb1;
  {
    if (tid < 128) {
      size_t o = (size_t)(rowBase + arow) * 128 + aq;
      p0 = *(const float4*)(P + o);
      p1 = *(const float4*)(P + PS + o);
      p2 = *(const float4*)(P + 2 * PS + o);
      p3 = *(const float4*)(P + 3 * PS + o);
      s4 = *(const float4*)(sc + aq);
      b4 = *(const float4*)(bb + aq);
    }
    pb0 = *(const float4*)(W + (size_t)bk * 128 + bc);
    pb1 = *(const float4*)(W + (size_t)(bk + 8) * 128 + bc);
  }
  for (int t = 0; t < 8; ++t) {
    if (tid < 128) {
      As[aq + 0][arow] = fmaxf((((p0.x + p1.x) + p2.x) + p3.x) * s4.x + b4.x, 0.0f);
      As[aq + 1][arow] = fmaxf((((p0.y + p1.y) + p2.y) + p3.y) * s4.y + b4.y, 0.0f);
      As[aq + 2][arow] = fmaxf((((p0.z + p1.z) + p2.z) + p3.z) * s4.z + b4.z, 0.0f);
      As[aq + 3][arow] = fmaxf((((p0.w + p1.w) + p2.w) + p3.w) * s4.w + b4.w, 0.0f);
    }
    *(float4*)&Bs[bk][bc] = pb0;
    *(float4*)&Bs[bk + 8][bc] = pb1;
    __syncthreads();
    if (t + 1 < 8) {
      int k0 = (t + 1) << 4;
      if (tid < 128) {
        size_t o = (size_t)(rowBase + arow) * 128 + k0 + aq;
        p0 = *(const float4*)(P + o);
        p1 = *(const float4*)(P + PS + o);
        p2 = *(const float4*)(P + 2 * PS + o);
        p3 = *(const float4*)(P + 3 * PS + o);
        s4 = *(const float4*)(sc + k0 + aq);
        b4 = *(const float4*)(bb + k0 + aq);
      }
      pb0 = *(const float4*)(W + (size_t)(k0 + bk) * 128 + bc);
      pb1 = *(const float4*)(W + (size_t)(k0 + bk + 8) * 128 + bc);
    }
#pragma unroll
    for (int kk = 0; kk < 16; ++kk) {
      float a[4];
      v2f bv[2];
      *(float4*)&a[0] = *(const float4*)&As[kk][ty * 4];
      *(float4*)&bv[0] = *(const float4*)&Bs[kk][tx * 4];
#pragma unroll
      for (int r = 0; r < 4; ++r)
#pragma unroll
        for (int c = 0; c < 2; ++c) acc[r][c] += a[r] * bv[c];
    }
    __syncthreads();
  }
#pragma unroll
  for (int r = 0; r < 4; ++r) {
    int row = rowBase + ty * 4 + r;
    int col = tx * 4;
    float av[4];
    *(v2f*)&av[0] = acc[r][0];
    *(v2f*)&av[2] = acc[r][1];
    float4 v;
    v.x = av[0] + bias[col + 0];
    v.y = av[1] + bias[col + 1];
    v.z = av[2] + bias[col + 2];
    v.w = av[3] + bias[col + 3];
    *(float4*)&C[(size_t)row * 128 + col] = v;
  }
}

// ---------------- Wg GEMM with fused h-combine (fused2 fallback) ---------------
__global__ __launch_bounds__(256) void gemm_hsum_kernel(
    const float* __restrict__ P0, const float* __restrict__ P1,
    const float* __restrict__ hbias, const float* __restrict__ W,
    const float* __restrict__ bias, float* __restrict__ C, int M) {
  __shared__ float As[16][36];
  __shared__ float Bs[16][132];
  int tid = threadIdx.x;
  int tx = tid & 31;
  int ty = tid >> 5;
  int rowBase = blockIdx.y * 32;
  v2f acc[4][2] = {};

  int arow = tid >> 2, aq = (tid & 3) * 4;
  int bk = tid >> 5, bc = (tid & 31) * 4;

  float4 pq0, pq1, pb0, pb1, hb;
  {
    if (tid < 128) {
      size_t o = (size_t)(rowBase + arow) * 512 + aq;
      pq0 = *(const float4*)(P0 + o);
      pq1 = *(const float4*)(P1 + o);
      hb = *(const float4*)(hbias + aq);
    }
    pb0 = *(const float4*)(W + (size_t)bk * 128 + bc);
    pb1 = *(const float4*)(W + (size_t)(bk + 8) * 128 + bc);
  }
  for (int t = 0; t < 32; ++t) {
    if (tid < 128) {
      As[aq + 0][arow] = fmaxf(pq0.x + pq1.x + hb.x, 0.0f);
      As[aq + 1][arow] = fmaxf(pq0.y + pq1.y + hb.y, 0.0f);
      As[aq + 2][arow] = fmaxf(pq0.z + pq1.z + hb.z, 0.0f);
      As[aq + 3][arow] = fmaxf(pq0.w + pq1.w + hb.w, 0.0f);
    }
    *(float4*)&Bs[bk][bc] = pb0;
    *(float4*)&Bs[bk + 8][bc] = pb1;
    __syncthreads();
    if (t + 1 < 32) {
      int k0 = (t + 1) << 4;
      if (tid < 128) {
        size_t o = (size_t)(rowBase + arow) * 512 + k0 + aq;
        pq0 = *(const float4*)(P0 + o);
        pq1 = *(const float4*)(P1 + o);
        hb = *(const float4*)(hbias + k0 + aq);
      }
      pb0 = *(const float4*)(W + (size_t)(k0 + bk) * 128 + bc);
      pb1 = *(const float4*)(W + (size_t)(k0 + bk + 8) * 128 + bc);
    }
#pragma unroll
    for (int kk = 0; kk < 16; ++kk) {
      float a[4];
      v2f bv[2];
      *(float4*)&a[0] = *(const float4*)&As[kk][ty * 4];
      *(float4*)&bv[0] = *(const float4*)&Bs[kk][tx * 4];
#pragma unroll
      for (int r = 0; r < 4; ++r)
#pragma unroll
        for (int c = 0; c < 2; ++c) acc[r][c] += a[r] * bv[c];
    }
    __syncthreads();
  }
#pragma unroll
  for (int r = 0; r < 4; ++r) {
    int row = rowBase + ty * 4 + r;
    int col = tx * 4;
    float av[4];
    *(v2f*)&av[0] = acc[r][0];
    *(v2f*)&av[2] = acc[r][1];
    size_t o = (size_t)row * 128 + col;
    float4 old = *(float4*)&C[o];
    float4 v;
    v.x = av[0] + bias[col + 0] + old.x;
    v.y = av[1] + bias[col + 1] + old.y;
    v.z = av[2] + bias[col + 2] + old.z;
    v.w = av[3] + bias[col + 3] + old.w;
    *(float4*)&C[o] = v;
  }
}

// ---------------- fp32 GEMM, 128x128 tile (fused fallback) ---------------------
__global__ __launch_bounds__(256) void gemm128_kernel(
    const float* __restrict__ A, const float* __restrict__ W,
    const float* __restrict__ A2, const float* __restrict__ W2,
    const float* __restrict__ bias, float* __restrict__ C,
    int M, int N, int K, int flags) {
  __shared__ float As[16][132];
  __shared__ float Bs[16][132];
  int tid = threadIdx.x;
  int tx = tid & 15;
  int ty = tid >> 4;
  int colBase = blockIdx.x * 128, rowBase = blockIdx.y * 128;
  v2f acc[8][4] = {};
  int ktiles = K >> 4;
  int total = (A2 ? 2 : 1) * ktiles;

  int arow = tid >> 1, aq = (tid & 1) * 8;
  int bk = tid >> 4, bq4 = (tid & 15) * 4;

  float4 pa0, pa1, pb0, pb1;
  {
    const float* ap = A + (size_t)(rowBase + arow) * K + aq;
    pa0 = *(const float4*)ap;
    pa1 = *(const float4*)(ap + 4);
    const float* bp = W + (size_t)bk * N + colBase;
    pb0 = *(const float4*)(bp + bq4);
    pb1 = *(const float4*)(bp + 64 + bq4);
  }
  for (int t = 0; t < total; ++t) {
    As[aq + 0][arow] = pa0.x; As[aq + 1][arow] = pa0.y;
    As[aq + 2][arow] = pa0.z; As[aq + 3][arow] = pa0.w;
    As[aq + 4][arow] = pa1.x; As[aq + 5][arow] = pa1.y;
    As[aq + 6][arow] = pa1.z; As[aq + 7][arow] = pa1.w;
    *(float4*)&Bs[bk][bq4] = pb0;
    *(float4*)&Bs[bk][64 + bq4] = pb1;
    __syncthreads();
    if (t + 1 < total) {
      int tn = t + 1;
      const float* Ap = (tn >= ktiles) ? A2 : A;
      const float* Wp = (tn >= ktiles) ? W2 : W;
      int k0 = ((tn >= ktiles) ? tn - ktiles : tn) << 4;
      const float* ap = Ap + (size_t)(rowBase + arow) * K + k0 + aq;
      pa0 = *(const float4*)ap;
      pa1 = *(const float4*)(ap + 4);
      const float* bp = Wp + (size_t)(k0 + bk) * N + colBase;
      pb0 = *(const float4*)(bp + bq4);
      pb1 = *(const float4*)(bp + 64 + bq4);
    }
#pragma unroll
    for (int kk = 0; kk < 16; ++kk) {
      float a[8];
      v2f bv[4];
      *(float4*)&a[0] = *(const float4*)&As[kk][ty * 8];
      *(float4*)&a[4] = *(const float4*)&As[kk][ty * 8 + 4];
      *(float4*)&bv[0] = *(const float4*)&Bs[kk][tx * 4];
      *(float4*)&bv[2] = *(const float4*)&Bs[kk][64 + tx * 4];
#pragma unroll
      for (int r = 0; r < 8; ++r)
#pragma unroll
        for (int c = 0; c < 4; ++c) acc[r][c] += a[r] * bv[c];
    }
    __syncthreads();
  }
#pragma unroll
  for (int r = 0; r < 8; ++r) {
    int row = rowBase + ty * 8 + r;
#pragma unroll
    for (int h = 0; h < 2; ++h) {
      int col = colBase + h * 64 + tx * 4;
      float av[4];
      *(v2f*)&av[0] = acc[r][h * 2 + 0];
      *(v2f*)&av[2] = acc[r][h * 2 + 1];
      float4 v;
      float* vp = (float*)&v;
#pragma unroll
      for (int c = 0; c < 4; ++c) {
        float t = av[c];
        if (bias) t += bias[col + c];
        if (flags & GF_RELU) t = fmaxf(t, 0.0f);
        vp[c] = t;
      }
      size_t o = (size_t)row * N + col;
      if (flags & GF_ACCUM) {
        float4 old = *(float4*)&C[o];
        v.x += old.x; v.y += old.y; v.z += old.z; v.w += old.w;
      }
      *(float4*)&C[o] = v;
    }
  }
}

// ---------------- fused FFN fp32 (fallback) ------------------------------------
__global__ __launch_bounds__(256) void ffn_fused_kernel(
    const float* __restrict__ xn, const float* __restrict__ W1,
    const float* __restrict__ b1, const float* __restrict__ W2,
    const float* __restrict__ b2, float* __restrict__ x) {
  __shared__ float Axn[128 * 36];
  __shared__ float Hs [128 * 36];
  __shared__ float Bs [16 * 132];
  int tid = threadIdx.x;
  int rowBase = blockIdx.x * 32;
  int tx = tid & 31, ty = tid >> 5;
  {
    int row = tid >> 3, ks = (tid & 7) * 16;
    const float* s1 = xn + (size_t)(rowBase + row) * 128 + ks;
#pragma unroll
    for (int q = 0; q < 4; ++q) {
      float4 v = *(const float4*)(s1 + q * 4);
      int k = ks + q * 4;
      Axn[(k + 0) * 36 + row] = v.x; Axn[(k + 1) * 36 + row] = v.y;
      Axn[(k + 2) * 36 + row] = v.z; Axn[(k + 3) * 36 + row] = v.w;
    }
  }
  int bk = tid >> 4, bc = (tid & 15) * 8;
  v2f hacc[4][2] = {};
  {
    float4 p0 = *(const float4*)(W1 + (size_t)bk * 128 + bc);
    float4 p1 = *(const float4*)(W1 + (size_t)bk * 128 + bc + 4);
    for (int kt = 0; kt < 8; ++kt) {
      __syncthreads();
      *(float4*)&Bs[bk * 132 + bc] = p0;
      *(float4*)&Bs[bk * 132 + bc + 4] = p1;
      __syncthreads();
      if (kt < 7) {
        p0 = *(const float4*)(W1 + (size_t)(kt * 16 + 16 + bk) * 128 + bc);
        p1 = *(const float4*)(W1 + (size_t)(kt * 16 + 16 + bk) * 128 + bc + 4);
      }
      int k0 = kt * 16;
#pragma unroll
      for (int kk = 0; kk < 16; ++kk) {
        float av[4];
        v2f bv[2];
        *(float4*)av = *(const float4*)&Axn[(k0 + kk) * 36 + ty * 4];
        *(float4*)&bv[0] = *(const float4*)&Bs[kk * 132 + tx * 4];
#pragma unroll
        for (int r = 0; r < 4; ++r)
#pragma unroll
          for (int c = 0; c < 2; ++c) hacc[r][c] += av[r] * bv[c];
      }
    }
  }
  __syncthreads();
#pragma unroll
  for (int r = 0; r < 4; ++r) {
    float hv[4];
    *(v2f*)&hv[0] = hacc[r][0];
    *(v2f*)&hv[2] = hacc[r][1];
#pragma unroll
    for (int c = 0; c < 4; ++c) {
      float v = hv[c] + b1[tx * 4 + c];
      v = fmaxf(v, 0.0f);
      Hs[(tx * 4 + c) * 36 + ty * 4 + r] = v;
    }
  }
  v2f oacc[4][2] = {};
  {
    float4 q0 = *(const float4*)(W2 + (size_t)bk * 128 + bc);
    float4 q1 = *(const float4*)(W2 + (size_t)bk * 128 + bc + 4);
    for (int kt = 0; kt < 8; ++kt) {
      __syncthreads();
      *(float4*)&Bs[bk * 132 + bc] = q0;
      *(float4*)&Bs[bk * 132 + bc + 4] = q1;
      __syncthreads();
      if (kt < 7) {
        q0 = *(const float4*)(W2 + (size_t)(kt * 16 + 16 + bk) * 128 + bc);
        q1 = *(const float4*)(W2 + (size_t)(kt * 16 + 16 + bk) * 128 + bc + 4);
      }
      int k0 = kt * 16;
#pragma unroll
      for (int kk = 0; kk < 16; ++kk) {
        float av[4];
        v2f bv[2];
        *(float4*)av = *(const float4*)&Hs[(k0 + kk) * 36 + ty * 4];
        *(float4*)&bv[0] = *(const float4*)&Bs[kk * 132 + tx * 4];
#pragma unroll
        for (int r = 0; r < 4; ++r)
#pragma unroll
          for (int c = 0; c < 2; ++c) oacc[r][c] += av[r] * bv[c];
      }
    }
  }
#pragma unroll
  for (int r = 0; r < 4; ++r) {
    int row = rowBase + ty * 4 + r;
    float ov[4];
    *(v2f*)&ov[0] = oacc[r][0];
    *(v2f*)&ov[2] = oacc[r][1];
    float4 old = *(float4*)&x[(size_t)row * 128 + tx * 4];
    float4 v;
    v.x = ov[0] + b2[tx * 4 + 0]; v.x += old.x;
    v.y = ov[1] + b2[tx * 4 + 1]; v.y += old.y;
    v.z = ov[2] + b2[tx * 4 + 2]; v.z += old.z;
    v.w = ov[3] + b2[tx * 4 + 3]; v.w += old.w;
    *(float4*)&x[(size_t)row * 128 + tx * 4] = v;
  }
}

// ---------------- q = x@Wq ; p = dinv*q (4 nodes/block, fallback paths) --------
__global__ __launch_bounds__(256) void qp_kernel(const float* __restrict__ x,
                                                 const float* __restrict__ Wq,
                                                 const float* __restrict__ dinv,
                                                 float* __restrict__ p, int Ni) {
  int node = blockIdx.x * 4 + (threadIdx.x >> 6);
  int lane = threadIdx.x & 63;
  int b = node / Ni, i = node % Ni;
  float v = x[(size_t)node * 128 + lane] * Wq[lane] +
            x[(size_t)node * 128 + 64 + lane] * Wq[64 + lane];
  for (int off = 32; off >= 1; off >>= 1) v += __shfl_xor(v, off, 64);
  if (lane == 0) p[b * Nmax + i] = dinv[b * Nmax + i] * v;
}

// ---------------- s = dinv * (A @ p) + bq (4 rows/block) -----------------------
__global__ __launch_bounds__(256) void score_kernel(const u32* __restrict__ adj,
                                                    const float* __restrict__ p,
                                                    const float* __restrict__ dinv,
                                                    const float* __restrict__ bq,
                                                    float* __restrict__ s, int Ni) {
  int i = blockIdx.x * 4 + (threadIdx.x >> 6);
  int b = blockIdx.y, lane = threadIdx.x & 63;
  int wpr = Ni >> 5;
  float acc = 0.0f;
  if (lane < wpr) {
    u32 bits = adj[((size_t)(b * Nmax + i)) * 64 + lane];
    while (bits) {
      int bit = __ffs(bits) - 1;
      bits &= bits - 1;
      acc += p[b * Nmax + (lane << 5) + bit];
    }
  }
  for (int off = 32; off >= 1; off >>= 1) acc += __shfl_xor(acc, off, 64);
  if (lane == 0) s[b * Nmax + i] = dinv[b * Nmax + i] * acc + bq[0];
}

// ---------------- top-k via exact rank counting, 4-way segment split -----------
__global__ void topk_rank_kernel(const float* __restrict__ s, int Ni, int* __restrict__ topi) {
  int b = blockIdx.y;
  int e0 = blockIdx.x * 64;
  int t = threadIdx.x;
  __shared__ u64 keys[2048];
  __shared__ int PR[256];
  for (int e = t; e < Ni; e += 256) {
    u32 u = __float_as_uint(s[b * Nmax + e]);
    u32 mono = (u & 0x80000000u) ? ~u : (u | 0x80000000u);
    keys[e] = ((u64)(~mono) << 32) | (u32)e;
  }
  __syncthreads();
  int quad = t >> 6, eloc = t & 63;
  u64 my = keys[e0 + eloc];
  int seg = Ni >> 2;
  int s0 = quad * seg;
  int rank = 0;
  for (int k = s0; k < s0 + seg; k += 4) {
    rank += (keys[k] < my) ? 1 : 0;
    rank += (keys[k + 1] < my) ? 1 : 0;
    rank += (keys[k + 2] < my) ? 1 : 0;
    rank += (keys[k + 3] < my) ? 1 : 0;
  }
  PR[t] = rank;
  __syncthreads();
  if (t < 64) {
    int tot = PR[t] + PR[t + 64] + PR[t + 128] + PR[t + 192];
    int kkeep = Ni >> 1;
    if (tot < kkeep) topi[b * 1024 + tot] = e0 + t;
  }
}

// ---------------- gather + tanh gate + optional LN1 + fused picks partial ------
__global__ __launch_bounds__(256) void gather_pick_kernel(
    const float* __restrict__ x, const float* __restrict__ c,
    const float* __restrict__ s, const int* __restrict__ topi,
    float* __restrict__ xo, float* __restrict__ co,
    const float* __restrict__ g, const float* __restrict__ be,
    float* __restrict__ xn, float* __restrict__ part, int Ni) {
  int gblk = blockIdx.x, b = blockIdx.y;
  int w = threadIdx.x >> 6, lane = threadIdx.x & 63;
  int kkeep = Ni >> 1;
  float mx1 = -INFINITY, mx2 = -INFINITY, sm1 = 0.0f, sm2 = 0.0f;
  for (int r2 = 0; r2 < 8; ++r2) {
    int inew = gblk * 32 + w * 8 + r2;
    int old = topi[b * 1024 + inew];
    float gate = tanhf(s[b * Nmax + old]);
    size_t ri = ((size_t)b * Ni + old) * 128;
    size_t ro = ((size_t)b * kkeep + inew) * 128;
    float v1 = x[ri + lane] * gate;
    float v2 = x[ri + 64 + lane] * gate;
    xo[ro + lane] = v1;
    xo[ro + 64 + lane] = v2;
    if (lane < 2) co[((size_t)b * kkeep + inew) * 2 + lane] = c[((size_t)b * Ni + old) * 2 + lane];
    mx1 = fmaxf(mx1, v1); mx2 = fmaxf(mx2, v2);
    sm1 += v1; sm2 += v2;
    if (g) {
      float sm = v1 + v2;
      for (int off = 32; off >= 1; off >>= 1) sm += __shfl_xor(sm, off, 64);
      float mean = sm / 128.0f;
      float d1 = v1 - mean, d2 = v2 - mean;
      float q = d1 * d1 + d2 * d2;
      for (int off = 32; off >= 1; off >>= 1) q += __shfl_xor(q, off, 64);
      float rs = rsqrtf(q / 128.0f + EPSV);
      xn[ro + lane] = d1 * rs * g[lane] + be[lane];
      xn[ro + 64 + lane] = d2 * rs * g[lane + 64] + be[lane + 64];
    }
  }
  __shared__ float LM[4][128], LS[4][128];
  LM[w][lane] = mx1; LM[w][64 + lane] = mx2;
  LS[w][lane] = sm1; LS[w][64 + lane] = sm2;
  __syncthreads();
  int t = threadIdx.x;
  if (t < 128) {
    float m = fmaxf(fmaxf(LM[0][t], LM[1][t]), fmaxf(LM[2][t], LM[3][t]));
    float ss = (LS[0][t] + LS[1][t]) + (LS[2][t] + LS[3][t]);
    size_t base = ((size_t)(b * (kkeep >> 5) + gblk)) * 256;
    part[base + t] = m;
    part[base + 128 + t] = ss;
  }
}

__global__ void picks_combine_kernel(const float* __restrict__ part, float* __restrict__ picks,
                                     int kkeep, int G) {
  int b = blockIdx.x, t = threadIdx.x;
  float mx = -INFINITY, sm = 0.0f;
  for (int g = 0; g < G; ++g) {
    mx = fmaxf(mx, part[((size_t)(b * G + g)) * 256 + t]);
    sm += part[((size_t)(b * G + g)) * 256 + 128 + t];
  }
  picks[b * 256 + t] += mx;
  picks[b * 256 + 128 + t] += sm / (float)kkeep;
}

// ---------------- final 2-layer MLP -------------------------------------------
__global__ void final_kernel(const float* __restrict__ picks, const float* __restrict__ Wf1,
                             const float* __restrict__ bf1, const float* __restrict__ Wf2,
                             const float* __restrict__ bf2, float* __restrict__ out) {
  int b = blockIdx.x, t = threadIdx.x;
  __shared__ float pk[256];
  __shared__ float fm[128];
  pk[t] = picks[b * 256 + t];
  pk[t + 128] = picks[b * 256 + 128 + t];
  __syncthreads();
  float acc = bf1[t];
  for (int k = 0; k < 256; ++k) acc += pk[k] * Wf1[k * 128 + t];
  fm[t] = fmaxf(acc, 0.0f);
  __syncthreads();
  if (t < 32) {
    float a2 = bf2[t];
    for (int k = 0; k < 128; ++k) a2 += fm[k] * Wf2[k * 32 + t];
    out[b * 32 + t] = fmaxf(a2, 0.0f);
  }
}

extern "C" void kernel_launch(void* const* d_in, const int* in_sizes, int n_in,
                              void* d_out, int out_size, void* d_ws, size_t ws_size,
                              hipStream_t stream) {
  const float* feats = (const float*)d_in[0];
  const float* cent  = (const float*)d_in[1];
  const float* Wp1 = (const float*)d_in[2];
  const float* bp1 = (const float*)d_in[3];
  const float* bn_g = (const float*)d_in[4];
  const float* bn_b = (const float*)d_in[5];
  const float* Wp2 = (const float*)d_in[6];
  const float* bp2 = (const float*)d_in[7];
  const float* g1  = (const float*)d_in[8];
  const float* be1 = (const float*)d_in[9];
  const float* g2  = (const float*)d_in[10];
  const float* be2 = (const float*)d_in[11];
  const float* Ws  = (const float*)d_in[12];
  const float* Wn  = (const float*)d_in[13];
  const float* bs  = (const float*)d_in[14];
  const float* Wg  = (const float*)d_in[15];
  const float* bg  = (const float*)d_in[16];
  const float* W1  = (const float*)d_in[17];
  const float* b1  = (const float*)d_in[18];
  const float* W2  = (const float*)d_in[19];
  const float* b2  = (const float*)d_in[20];
  const float* Wq  = (const float*)d_in[21];
  const float* bq  = (const float*)d_in[22];
  const float* Wf1 = (const float*)d_in[23];
  const float* bf1 = (const float*)d_in[24];
  const float* Wf2 = (const float*)d_in[25];
  const float* bf2 = (const float*)d_in[26];
  float* out = (float*)d_out;

  float* p = (float*)d_ws;
  const size_t SZX = (size_t)Bn * Nmax * 128;
  float* SC = p;    p += 128;
  float* BBv = p;   p += 128;
  float* DINV = p;  p += Bn * Nmax;
  float* PV = p;    p += Bn * Nmax;
  float* SS = p;    p += Bn * Nmax;
  float* PICKS = p; p += Bn * 256;
  float* PART = p;  p += (size_t)Bn * 32 * 256;
  float* C0 = p;    p += (size_t)Bn * Nmax * 2;
  float* C1 = p;    p += (size_t)Bn * Nmax * 2;
  int* KNN = (int*)p;  p += (size_t)Bn * Nmax * KNN_K;   // unused (kept for layout)
  int* TOPI = (int*)p; p += Bn * 1024;
  u32* ADJ = (u32*)p;  p += (size_t)Bn * Nmax * 64;
  float* X0 = p;    p += SZX;
  float* X1 = p;    p += SZX;
  float* BA = p;    p += SZX;
  float* BB = p;    p += SZX;
  float* HB = p;    // fused3: H hi/lo planes; preconv packed H; fallback: partials
  size_t base_floats = (size_t)(p - (float*)d_ws);
  const size_t WPSZ = (size_t)3 * 128 * 512;
  bool fused = ws_size >= (base_floats + 4 * SZX + 2 * WPSZ) * sizeof(float);
  float* WSP = HB + 4 * SZX;   // fused3: Wc split pairs (3*512*256 u32)
  float* WNP = WSP + WPSZ;
  float* PK = WNP + WPSZ;      // fused3: repacked split weights; fused2: h partial 1
  bool fused2 = ws_size >= (base_floats + 8 * SZX + 2 * WPSZ) * sizeof(float);
  bool fused3 = ws_size >= (base_floats + 9 * SZX + 2 * WPSZ) * sizeof(float);

  // split weight pointers inside PK region (fused3); planes share the old u32 space
  u16* WgTh = (u16*)PK;               // 3*128*512 values
  u16* WgTl = WgTh + 196608;
  u32* Wp1Tu = (u32*)PK + 196608;     // 128*512 packed
  u32* Wp2Tu = Wp1Tu + 65536;         // 128*128 packed
  u32* W1Tu  = Wp2Tu + 16384;         // region 3*128*128 u32
  u16* W1Th = (u16*)W1Tu;
  u16* W1Tl = W1Th + 49152;
  u32* W2Tu  = W1Tu + 49152;
  u16* W2Th = (u16*)W2Tu;
  u16* W2Tl = W2Th + 49152;
  // H planes in HB (16MB each at Nmax)
  u16* Hh = (u16*)HB;
  u16* Hl = Hh + (size_t)Bn * Nmax * 512;

  hipLaunchKernelGGL(precompute_kernel, dim3(1), dim3(256), 0, stream,
                     bn_g, bn_b, bp1, SC, BBv, PICKS);
  if (fused3) {
    hipLaunchKernelGGL(repack_split_kernel, dim3(3008), dim3(256), 0, stream,
                       Ws, Wn, Wg, Wp1, Wp2, W1, W2,
                       (u32*)WSP, WgTh, WgTl, Wp1Tu, Wp2Tu, W1Th, W1Tl, W2Th, W2Tl);
  } else if (fused) {
    hipLaunchKernelGGL(repack_ws_kernel, dim3(768), dim3(256), 0, stream, Ws, Wn, WSP, WNP);
  }

  // ---- preconv ----
  const int M0 = Bn * Nmax;
  if (fused3) {
    hipLaunchKernelGGL(preconv1_kernel, dim3(M0 / 64), dim3(256), 0, stream,
                       feats, Wp1Tu, SC, BBv, (u32*)HB, M0);
    hipLaunchKernelGGL(preconv2_ln_kernel, dim3(M0 / 64), dim3(256), 0, stream,
                       (const u32*)HB, Wp2Tu, bp2, g1, be1, X0, BA, M0);
  } else if (fused) {
    hipLaunchKernelGGL(gemm128ks_kernel, dim3(1, M0 / 128, 4), dim3(256), 0, stream,
                       feats, Wp1, HB, M0, 512);
    hipLaunchKernelGGL(gemm_psum4_kernel, dim3(1, M0 / 32), dim3(256), 0, stream,
                       HB, SC, BBv, Wp2, bp2, X0, M0);
  } else {
    hipLaunchKernelGGL(gemm_kernel<32>, dim3(1, M0 / 32), dim3(256), 0, stream,
                       feats, Wp1, (const float*)nullptr, (const float*)nullptr,
                       SC, BBv, BA, M0, 128, 512, GF_RELU);
    hipLaunchKernelGGL(gemm_kernel<32>, dim3(1, M0 / 32), dim3(256), 0, stream,
                       BA, Wp2, (const float*)nullptr, (const float*)nullptr,
                       (const float*)nullptr, bp2, X0, M0, 128, 128, 0);
  }

  float* xc = X0;
  float* xo = X1;
  const float* cc = cent;
  float* co = C0;
  int Ni = Nmax;
  for (int L = 0; L < 3; ++L) {
    int M = Bn * Ni;
    int niShift = (Ni == 2048) ? 11 : (Ni == 1024) ? 10 : 9;
    // zero ADJ first: knn writes adjacency bits directly (no build_adj pass)
    hipMemsetAsync(ADJ, 0, (size_t)Bn * Nmax * 64 * sizeof(u32), stream);
    if (Ni == 2048)      hipLaunchKernelGGL(knn_sel_kernel<32>, dim3(Ni / 4, Bn), dim3(256), 0, stream, cc, ADJ, Ni);
    else if (Ni == 1024) hipLaunchKernelGGL(knn_sel_kernel<16>, dim3(Ni / 4, Bn), dim3(256), 0, stream, cc, ADJ, Ni);
    else                 hipLaunchKernelGGL(knn_sel_kernel<8>,  dim3(Ni / 4, Bn), dim3(256), 0, stream, cc, ADJ, Ni);
    if (!fused3) {
      hipLaunchKernelGGL(layernorm_kernel, dim3(M / 4), dim3(256), 0, stream,
                         xc, g1 + L * 128, be1 + L * 128, BA);
    }
    hipLaunchKernelGGL(aggregate_kernel, dim3(Ni / 2, Bn), dim3(256), 2 * Ni * sizeof(int), stream,
                       ADJ, BA, fused3 ? (float*)nullptr : BB,
                       fused3 ? (u32*)BB : (u32*)nullptr, DINV, Ni);
    if (fused3) {
      hipLaunchKernelGGL(attn_gemm1_kernel, dim3(4, M / 128), dim3(256), 0, stream,
                         BA, (const u32*)BB, (const u32*)WSP + (size_t)L * 512 * 256,
                         bs + L * 512, Hh, Hl, M);
      hipLaunchKernelGGL(attn2_ffn16_kernel, dim3(M / 16), dim3(256), 0, stream,
                         Hh, Hl,
                         WgTh + (size_t)L * 65536, WgTl + (size_t)L * 65536,
                         bg + L * 128, g2 + L * 128, be2 + L * 128,
                         W1Th + (size_t)L * 16384, W1Tl + (size_t)L * 16384,
                         b1 + L * 128,
                         W2Th + (size_t)L * 16384, W2Tl + (size_t)L * 16384,
                         b2 + L * 128, xc,
                         Wq + L * 128, DINV, PV, niShift, M);
    } else if (fused2) {
      hipLaunchKernelGGL(gemm128dual_kernel, dim3(4, M / 128, 2), dim3(256), 0, stream,
                         BA, WSP + (size_t)L * 128 * 512,
                         BB, WNP + (size_t)L * 128 * 512,
                         HB, PK, M, 512);
      hipLaunchKernelGGL(gemm_hsum_kernel, dim3(1, M / 32), dim3(256), 0, stream,
                         HB, PK, bs + L * 512, Wg + (size_t)L * 512 * 128,
                         bg + L * 128, xc, M);
      hipLaunchKernelGGL(layernorm_kernel, dim3(M / 4), dim3(256), 0, stream,
                         xc, g2 + L * 128, be2 + L * 128, BA);
      hipLaunchKernelGGL(ffn_fused_kernel, dim3(M / 32), dim3(256), 0, stream,
                         BA, W1 + (size_t)L * 128 * 128, b1 + L * 128,
                         W2 + (size_t)L * 128 * 128, b2 + L * 128, xc);
    } else if (fused) {
      hipLaunchKernelGGL(gemm128_kernel, dim3(4, M / 128), dim3(256), 0, stream,
                         BA, WSP + (size_t)L * 128 * 512,
                         BB, WNP + (size_t)L * 128 * 512,
                         bs + L * 512, HB, M, 512, 128, GF_RELU);
      hipLaunchKernelGGL(gemm_kernel<32>, dim3(1, M / 32), dim3(256), 0, stream,
                         HB, Wg + (size_t)L * 512 * 128,
                         (const float*)nullptr, (const float*)nullptr,
                         (const float*)nullptr, bg + L * 128,
                         xc, M, 128, 512, GF_ACCUM);
      hipLaunchKernelGGL(layernorm_kernel, dim3(M / 4), dim3(256), 0, stream,
                         xc, g2 + L * 128, be2 + L * 128, BA);
      hipLaunchKernelGGL(ffn_fused_kernel, dim3(M / 32), dim3(256), 0, stream,
                         BA, W1 + (size_t)L * 128 * 128, b1 + L * 128,
                         W2 + (size_t)L * 128 * 128, b2 + L * 128, xc);
    } else {
      for (int hh = 0; hh < 4; ++hh) {
        hipLaunchKernelGGL(gemm_kernel<32>, dim3(1, M / 32), dim3(256), 0, stream,
                           BA, Ws + ((size_t)(L * 4 + hh)) * 128 * 128,
                           BB, Wn + ((size_t)(L * 4 + hh)) * 128 * 128,
                           (const float*)nullptr, bs + (L * 4 + hh) * 128,
                           HB, M, 128, 128, GF_RELU);
        hipLaunchKernelGGL(gemm_kernel<32>, dim3(1, M / 32), dim3(256), 0, stream,
                           HB, Wg + ((size_t)L * 512 + hh * 128) * 128,
                           (const float*)nullptr, (const float*)nullptr,
                           (const float*)nullptr, (hh == 0) ? (bg + L * 128) : (const float*)nullptr,
                           xc, M, 128, 128, GF_ACCUM);
      }
      hipLaunchKernelGGL(layernorm_kernel, dim3(M / 4), dim3(256), 0, stream,
                         xc, g2 + L * 128, be2 + L * 128, BA);
      hipLaunchKernelGGL(ffn_fused_kernel, dim3(M / 32), dim3(256), 0, stream,
                         BA, W1 + (size_t)L * 128 * 128, b1 + L * 128,
                         W2 + (size_t)L * 128 * 128, b2 + L * 128, xc);
    }
    if (!fused3) {
      hipLaunchKernelGGL(qp_kernel, dim3(M / 4), dim3(256), 0, stream, xc, Wq + L * 128, DINV, PV, Ni);
    }
    hipLaunchKernelGGL(score_kernel, dim3(Ni / 4, Bn), dim3(256), 0, stream, ADJ, PV, DINV, bq + L, SS, Ni);
    hipLaunchKernelGGL(topk_rank_kernel, dim3(Ni / 64, Bn), dim3(256), 0, stream,
                       SS, Ni, TOPI);
    int kkeep = Ni >> 1;
    const float* gn = (fused3 && L < 2) ? (g1 + (L + 1) * 128) : (const float*)nullptr;
    const float* bn = (fused3 && L < 2) ? (be1 + (L + 1) * 128) : (const float*)nullptr;
    hipLaunchKernelGGL(gather_pick_kernel, dim3(kkeep / 32, Bn), dim3(256), 0, stream,
                       xc, cc, SS, TOPI, xo, co, gn, bn, BA, PART, Ni);
    int G = kkeep / 32;
    hipLaunchKernelGGL(picks_combine_kernel, dim3(Bn), dim3(128), 0, stream,
                       PART, PICKS, kkeep, G);
    float* tmp = xc; xc = xo; xo = tmp;
    cc = co;
    co = (co == C0) ? C1 : C0;
    Ni = kkeep;
  }
  hipLaunchKernelGGL(final_kernel, dim3(Bn), dim3(128), 0, stream,
                     PICKS, Wf1, bf1, Wf2, bf2, out);
}